// Round 14
// baseline (9336.646 us; speedup 1.0000x reference)
//
#include <hip/hip_runtime.h>
#include <hip/hip_bf16.h>
#include <stdint.h>

// Problem constants: B=4, S=2048, IN=4096, OUT=11008
#define M_DIM 8192   // B*S
#define N_DIM 11008  // OUT
#define K_DIM 4096   // IN
#define NGROUP 32    // K_DIM/128

#define BM 256
#define BN 256
#define BK 64
#define NT (K_DIM / BK)  // 64 K-tiles

typedef __attribute__((ext_vector_type(4))) float f32x4;
typedef __attribute__((ext_vector_type(8))) short short8;
typedef __attribute__((ext_vector_type(8))) __bf16 bf16x8;

static_assert(M_DIM % BM == 0 && N_DIM % BN == 0 && K_DIM % BK == 0, "tiling");

__device__ __forceinline__ unsigned short f2bf(float f) {
  union { float f; unsigned int u; } v; v.f = f;
  unsigned int r = v.u + 0x7FFFu + ((v.u >> 16) & 1u);  // RNE
  return (unsigned short)(r >> 16);
}

// ---------- prepass 1: x fp32 -> bf16 ----------
__global__ __launch_bounds__(256) void cvt_x_kernel(const float* __restrict__ x,
                                                    unsigned short* __restrict__ xb) {
  size_t i = ((size_t)blockIdx.x * 256 + threadIdx.x) * 8;
  float4 a = *(const float4*)(x + i);
  float4 b = *(const float4*)(x + i + 4);
  short8 o;
  o[0] = (short)f2bf(a.x); o[1] = (short)f2bf(a.y);
  o[2] = (short)f2bf(a.z); o[3] = (short)f2bf(a.w);
  o[4] = (short)f2bf(b.x); o[5] = (short)f2bf(b.y);
  o[6] = (short)f2bf(b.z); o[7] = (short)f2bf(b.w);
  *(short8*)(xb + i) = o;
}

// ---------- prepass 2: dequant packed int4 -> bf16 W[N][K] ----------
__global__ __launch_bounds__(256) void dequant_kernel(const int* __restrict__ qw,
                                                      const float* __restrict__ sc,
                                                      const float* __restrict__ zp,
                                                      unsigned short* __restrict__ W) {
  size_t chunk = (size_t)blockIdx.x * 256 + threadIdx.x;  // 4 packed int32 = 8 weights
  int row = (int)(chunk >> 9);
  int c4  = (int)(chunk & 511);
  int g   = c4 >> 4;
  float s = sc[row * NGROUP + g];
  float z = zp[row * NGROUP + g];
  int4 q = *(const int4*)(qw + (size_t)row * 2048 + c4 * 4);
  int qq[4] = {q.x, q.y, q.z, q.w};
  short8 o;
#pragma unroll
  for (int t = 0; t < 4; ++t) {
    o[2 * t]     = (short)f2bf(((float)(qq[t] & 15)        - z) * s);
    o[2 * t + 1] = (short)f2bf(((float)((qq[t] >> 4) & 15) - z) * s);
  }
  *(short8*)(W + (size_t)row * K_DIM + (size_t)c4 * 8) = o;
}

// ---------- 256x256 GEMM: A-fragments direct from global (L2), B via LDS ----------
__device__ __forceinline__ void gload_lds16(const void* g, void* l) {
  __builtin_amdgcn_global_load_lds((__attribute__((address_space(1))) void*)g,
                                   (__attribute__((address_space(3))) void*)l,
                                   16, 0, 0);
}

// Stage one B k-half panel [256 rows][32 cols] (16KB), 2 gload_lds per thread.
__device__ __forceinline__ void stage2(const unsigned short* s0,
                                       const unsigned short* s1,
                                       unsigned short* panel, int wave, int koff) {
  gload_lds16(s0 + koff, panel + wave * 512);
  gload_lds16(s1 + koff, panel + 4096 + wave * 512);
}

#define VMC(N) asm volatile("s_waitcnt vmcnt(" #N ")" ::: "memory")

// A-fragment load direct from global: lane reads 16B along K at 4 rows (mi*16+fr).
#define LD_GA(DST, MH, KOFF)                                                 \
  _Pragma("unroll") for (int mi_ = 0; mi_ < 4; ++mi_)                        \
    DST[mi_] = *(const bf16x8*)(Afb + (size_t)((MH)*64 + mi_ * 16) * K_DIM + (KOFF));

// B fragment reads from LDS (pure ds_read; results consumed one phase later).
#define RD_BV(DST, P)                                                        \
  _Pragma("unroll") for (int n_ = 0; n_ < 4; ++n_)                           \
    DST[n_] = *(const bf16x8*)&(P)[bbase + n_ * 512];

// MFMA cluster on registers loaded one phase earlier.
#define MFMA_BLK(MH, AV, BV)                                                 \
  {                                                                          \
    __builtin_amdgcn_s_setprio(1);                                           \
    _Pragma("unroll") for (int m_ = 0; m_ < 4; ++m_)                         \
      _Pragma("unroll") for (int n_ = 0; n_ < 4; ++n_)                       \
        acc[(MH)*4 + m_][n_] = __builtin_amdgcn_mfma_f32_16x16x32_bf16(      \
            AV[m_], BV[n_], acc[(MH)*4 + m_][n_], 0, 0, 0);                  \
    __builtin_amdgcn_s_setprio(0);                                           \
  }

#define BP(buf, kh) (lds + ((buf) * 2 + (kh)) * 8192)

__global__ __launch_bounds__(512, 4) void gemm_adirect_kernel(const unsigned short* __restrict__ A,
                                                              const unsigned short* __restrict__ B,
                                                              float* __restrict__ C) {
  extern __shared__ unsigned short lds[];  // B only: [2 buf][2 kh][256*32] = 64KB

  const int tid  = threadIdx.x;
  const int wave = tid >> 6;
  const int lane = tid & 63;
  const int wm = wave >> 2;   // 0..1 -> 128-row slab
  const int wn = wave & 3;    // 0..3 -> 64-col slab
  const int fr = lane & 15;
  const int cp = (lane >> 4) ^ ((fr >> 1) & 3);  // swizzled physical 16B-block (0-conflict, B only)

  // XCD-chunked block swizzle (1376 = 8*172, bijective), bm-major:
  // 43 consecutive blocks per XCD share one 2MB A panel (L2-resident).
  const int wg  = blockIdx.x;
  const int sz_ = (wg & 7) * 172 + (wg >> 3);
  const int bm = sz_ / 43;
  const int bn = sz_ % 43;
  const size_t row0 = (size_t)bm * BM;
  const size_t col0 = (size_t)bn * BN;

  const unsigned short* Ab = A + row0 * K_DIM;
  const unsigned short* Bb = B + col0 * K_DIM;

  // per-lane A-fragment base: row (wm*128 + fr), k offset (lane>>4)*8
  const unsigned short* Afb = Ab + (size_t)(wm * 128 + fr) * K_DIM + (lane >> 4) * 8;

  // per-lane B staging sources (swizzle baked into global col, rule #21)
  const int cl = (tid & 3) ^ ((tid >> 3) & 3);
  const int r0 = tid >> 2;
  const unsigned short* bsrc0 = Bb + (size_t)r0 * K_DIM + cl * 8;
  const unsigned short* bsrc1 = Bb + (size_t)(r0 + 128) * K_DIM + cl * 8;

  // B fragment LDS element offset (panel-local); frag n at bbase + n*512
  const int bbase = (wn * 64 + fr) * 32 + cp * 8;

  f32x4 acc[8][4];
#pragma unroll
  for (int i = 0; i < 8; ++i)
#pragma unroll
    for (int j = 0; j < 4; ++j) acc[i][j] = (f32x4){0.f, 0.f, 0.f, 0.f};

  bf16x8 ga0[4], ga1[4];   // A fragments (global-loaded, ping-pong)
  bf16x8 bv0[4], bv1[4];   // B fragments (LDS-read, per k-half)

  // ---- prologue: stage B tile0 (both kh); load first A frag; drain; pre-read bv0 ----
  stage2(bsrc0, bsrc1, BP(0, 0), wave, 0);
  stage2(bsrc0, bsrc1, BP(0, 1), wave, 32);
  LD_GA(ga0, 0, 0);
  VMC(0);
  __builtin_amdgcn_s_barrier();
  RD_BV(bv0, BP(0, 0));

  // ---- main loop: 4 phases/K-tile; A from global 1 phase ahead; B staged 1 tile ahead ----
  for (int T = 0; T < NT - 1; ++T) {
    const int buf = T & 1, nb = buf ^ 1;
    const int k0 = T * 64;
    const int nk = k0 + 64;

    // P1: MFMA(k0,mh0){ga0,bv0}; load ga1<-A(k0,mh1); stage next B.kh0
    VMC(0);                                  // retire prev P3's next-ga0 group
    MFMA_BLK(0, ga0, bv0);
    LD_GA(ga1, 1, k0);
    stage2(bsrc0, bsrc1, BP(nb, 0), wave, nk);
    // P2: MFMA(k0,mh1){ga1,bv0}; load ga0<-A(k1,mh0); stage next B.kh1; read bv1
    VMC(2);                                  // retire P1's ga1 (leaves 2S)
    MFMA_BLK(1, ga1, bv0);
    LD_GA(ga0, 0, k0 + 32);
    stage2(bsrc0, bsrc1, BP(nb, 1), wave, nk + 32);
    RD_BV(bv1, BP(buf, 1));
    // P3: MFMA(k1,mh0){ga0,bv1}; load ga1<-A(k1,mh1) + ga0<-A(next,k0,mh0);
    //     barrier publishes next B.kh0 (its 2 loads retired by this VMC)
    VMC(2);                                  // retire P2's ga0 (+P1's 2S)
    MFMA_BLK(0, ga0, bv1);
    LD_GA(ga1, 1, k0 + 32);
    LD_GA(ga0, 0, nk);                       // next tile (k0', mh0)
    __builtin_amdgcn_s_barrier();            // publish BP(nb,0)
    RD_BV(bv0, BP(nb, 0));
    // P4: MFMA(k1,mh1){ga1,bv1}; barrier publishes next B.kh1
    VMC(4);                                  // retire P3's ga1 (+P2's 2S); leaves next-ga0
    MFMA_BLK(1, ga1, bv1);
    __builtin_amdgcn_s_barrier();            // publish BP(nb,1)
  }
  // ---- last tile: no staging, no barriers ----
  {
    const int buf = (NT - 1) & 1;
    const int k0 = (NT - 1) * 64;
    VMC(0);
    MFMA_BLK(0, ga0, bv0);
    LD_GA(ga1, 1, k0);
    VMC(0);
    MFMA_BLK(1, ga1, bv0);
    LD_GA(ga0, 0, k0 + 32);
    RD_BV(bv1, BP(buf, 1));
    VMC(0);
    MFMA_BLK(0, ga0, bv1);
    LD_GA(ga1, 1, k0 + 32);
    VMC(0);
    MFMA_BLK(1, ga1, bv1);
  }

  // ---- epilogue: C/D layout col = lane&15, row = (lane>>4)*4 + v ----
  const int orow = (lane >> 4) * 4;
#pragma unroll
  for (int mi = 0; mi < 8; ++mi) {
#pragma unroll
    for (int n = 0; n < 4; ++n) {
      const size_t r = row0 + wm * 128 + mi * 16 + orow;
      const size_t c = col0 + wn * 64 + n * 16 + fr;
#pragma unroll
      for (int v = 0; v < 4; ++v)
        C[(r + v) * N_DIM + c] = acc[mi][n][v];
    }
  }
}

// ---------- fallback (only if d_ws too small): naive fused ----------
__global__ __launch_bounds__(256) void fallback_kernel(const float* __restrict__ x,
                                                       const int* __restrict__ qw,
                                                       const float* __restrict__ sc,
                                                       const float* __restrict__ zp,
                                                       float* __restrict__ out) {
  __shared__ float xs[K_DIM];
  const int m = blockIdx.y;
  const int n = blockIdx.x * 256 + threadIdx.x;
  for (int i = threadIdx.x; i < K_DIM; i += 256) xs[i] = x[(size_t)m * K_DIM + i];
  __syncthreads();
  float acc = 0.f;
  const int* wrow = qw + (size_t)n * (K_DIM / 2);
  for (int g = 0; g < NGROUP; ++g) {
    float s = sc[n * NGROUP + g];
    float z = zp[n * NGROUP + g];
    float partial = 0.f;
    for (int p = 0; p < 64; ++p) {
      int q = wrow[g * 64 + p];
      partial += xs[g * 128 + 2 * p]     * ((float)(q & 15) - z);
      partial += xs[g * 128 + 2 * p + 1] * ((float)((q >> 4) & 15) - z);
    }
    acc = fmaf(partial, s, acc);
  }
  out[(size_t)m * N_DIM + n] = acc;
}

extern "C" void kernel_launch(void* const* d_in, const int* in_sizes, int n_in,
                              void* d_out, int out_size, void* d_ws, size_t ws_size,
                              hipStream_t stream) {
  const float* x  = (const float*)d_in[0];
  const int*   qw = (const int*)d_in[1];
  const float* sc = (const float*)d_in[2];
  const float* zp = (const float*)d_in[3];
  float* out = (float*)d_out;

  const size_t xb_bytes = (size_t)M_DIM * K_DIM * 2;
  const size_t wb_bytes = (size_t)N_DIM * K_DIM * 2;

  if (ws_size >= xb_bytes + wb_bytes) {
    unsigned short* xb = (unsigned short*)d_ws;
    unsigned short* wb = (unsigned short*)((char*)d_ws + xb_bytes);
    cvt_x_kernel<<<dim3((unsigned)((size_t)M_DIM * K_DIM / (256 * 8))), 256, 0, stream>>>(x, xb);
    dequant_kernel<<<dim3((unsigned)((size_t)N_DIM * (K_DIM / 2) / 4 / 256)), 256, 0, stream>>>(qw, sc, zp, wb);
    dim3 grid((M_DIM / BM) * (N_DIM / BN));  // 32*43 = 1376
    gemm_adirect_kernel<<<grid, dim3(512), 65536, stream>>>(xb, wb, out);
  } else {
    dim3 grid(N_DIM / 256, M_DIM);
    fallback_kernel<<<grid, 256, 0, stream>>>(x, qw, sc, zp, out);
  }
}

// Round 15
// 1701.353 us; speedup vs baseline: 5.4878x; 5.4878x over previous
//
#include <hip/hip_runtime.h>
#include <hip/hip_bf16.h>
#include <stdint.h>

// Problem constants: B=4, S=2048, IN=4096, OUT=11008
#define M_DIM 8192   // B*S
#define N_DIM 11008  // OUT
#define K_DIM 4096   // IN
#define NGROUP 32    // K_DIM/128

#define BM 256
#define BN 256
#define BK 64
#define NT (K_DIM / BK)  // 64 K-tiles

typedef __attribute__((ext_vector_type(4))) float f32x4;
typedef __attribute__((ext_vector_type(8))) short short8;
typedef __attribute__((ext_vector_type(8))) __bf16 bf16x8;

static_assert(M_DIM % BM == 0 && N_DIM % BN == 0 && K_DIM % BK == 0, "tiling");

__device__ __forceinline__ unsigned short f2bf(float f) {
  union { float f; unsigned int u; } v; v.f = f;
  unsigned int r = v.u + 0x7FFFu + ((v.u >> 16) & 1u);  // RNE
  return (unsigned short)(r >> 16);
}

// ---------- prepass 1: x fp32 -> bf16 ----------
__global__ __launch_bounds__(256) void cvt_x_kernel(const float* __restrict__ x,
                                                    unsigned short* __restrict__ xb) {
  size_t i = ((size_t)blockIdx.x * 256 + threadIdx.x) * 8;
  float4 a = *(const float4*)(x + i);
  float4 b = *(const float4*)(x + i + 4);
  short8 o;
  o[0] = (short)f2bf(a.x); o[1] = (short)f2bf(a.y);
  o[2] = (short)f2bf(a.z); o[3] = (short)f2bf(a.w);
  o[4] = (short)f2bf(b.x); o[5] = (short)f2bf(b.y);
  o[6] = (short)f2bf(b.z); o[7] = (short)f2bf(b.w);
  *(short8*)(xb + i) = o;
}

// ---------- prepass 2: dequant packed int4 -> bf16 W[N][K] ----------
__global__ __launch_bounds__(256) void dequant_kernel(const int* __restrict__ qw,
                                                      const float* __restrict__ sc,
                                                      const float* __restrict__ zp,
                                                      unsigned short* __restrict__ W) {
  size_t chunk = (size_t)blockIdx.x * 256 + threadIdx.x;  // 4 packed int32 = 8 weights
  int row = (int)(chunk >> 9);
  int c4  = (int)(chunk & 511);
  int g   = c4 >> 4;
  float s = sc[row * NGROUP + g];
  float z = zp[row * NGROUP + g];
  int4 q = *(const int4*)(qw + (size_t)row * 2048 + c4 * 4);
  int qq[4] = {q.x, q.y, q.z, q.w};
  short8 o;
#pragma unroll
  for (int t = 0; t < 4; ++t) {
    o[2 * t]     = (short)f2bf(((float)(qq[t] & 15)        - z) * s);
    o[2 * t + 1] = (short)f2bf(((float)((qq[t] >> 4) & 15) - z) * s);
  }
  *(short8*)(W + (size_t)row * K_DIM + (size_t)c4 * 8) = o;
}

// ---------- 256x256 GEMM: A-fragments direct from global (L2), B via LDS ----------
__device__ __forceinline__ void gload_lds16(const void* g, void* l) {
  __builtin_amdgcn_global_load_lds((__attribute__((address_space(1))) void*)g,
                                   (__attribute__((address_space(3))) void*)l,
                                   16, 0, 0);
}

// Stage one B k-half panel [256 rows][32 cols] (16KB), 2 gload_lds per thread.
__device__ __forceinline__ void stage2(const unsigned short* s0,
                                       const unsigned short* s1,
                                       unsigned short* panel, int wave, int koff) {
  gload_lds16(s0 + koff, panel + wave * 512);
  gload_lds16(s1 + koff, panel + 4096 + wave * 512);
}

#define VMC(N) asm volatile("s_waitcnt vmcnt(" #N ")" ::: "memory")

// A-fragment load direct from global: lane reads 16B along K at 4 rows (mi*16+fr).
#define LD_GA(DST, MH, KOFF)                                                 \
  _Pragma("unroll") for (int mi_ = 0; mi_ < 4; ++mi_)                        \
    DST[mi_] = *(const bf16x8*)(Afb + (size_t)((MH)*64 + mi_ * 16) * K_DIM + (KOFF));

// B fragment reads from LDS (pure ds_read; results consumed one phase later).
#define RD_BV(DST, P)                                                        \
  _Pragma("unroll") for (int n_ = 0; n_ < 4; ++n_)                           \
    DST[n_] = *(const bf16x8*)&(P)[bbase + n_ * 512];

// MFMA cluster on registers loaded one phase earlier.
#define MFMA_BLK(MH, AV, BV)                                                 \
  {                                                                          \
    __builtin_amdgcn_s_setprio(1);                                           \
    _Pragma("unroll") for (int m_ = 0; m_ < 4; ++m_)                         \
      _Pragma("unroll") for (int n_ = 0; n_ < 4; ++n_)                       \
        acc[(MH)*4 + m_][n_] = __builtin_amdgcn_mfma_f32_16x16x32_bf16(      \
            AV[m_], BV[n_], acc[(MH)*4 + m_][n_], 0, 0, 0);                  \
    __builtin_amdgcn_s_setprio(0);                                           \
  }

#define BP(buf, kh) (lds + ((buf) * 2 + (kh)) * 8192)

__global__ __launch_bounds__(512, 2) void gemm_adirect_kernel(const unsigned short* __restrict__ A,
                                                              const unsigned short* __restrict__ B,
                                                              float* __restrict__ C) {
  extern __shared__ unsigned short lds[];  // B only: [2 buf][2 kh][256*32] = 64KB

  const int tid  = threadIdx.x;
  const int wave = tid >> 6;
  const int lane = tid & 63;
  const int wm = wave >> 2;   // 0..1 -> 128-row slab
  const int wn = wave & 3;    // 0..3 -> 64-col slab
  const int fr = lane & 15;
  const int cp = (lane >> 4) ^ ((fr >> 1) & 3);  // swizzled physical 16B-block (0-conflict, B only)

  // XCD-chunked block swizzle (1376 = 8*172, bijective), bm-major:
  // 43 consecutive blocks per XCD share one 2MB A panel (L2-resident).
  const int wg  = blockIdx.x;
  const int sz_ = (wg & 7) * 172 + (wg >> 3);
  const int bm = sz_ / 43;
  const int bn = sz_ % 43;
  const size_t row0 = (size_t)bm * BM;
  const size_t col0 = (size_t)bn * BN;

  const unsigned short* Ab = A + row0 * K_DIM;
  const unsigned short* Bb = B + col0 * K_DIM;

  // per-lane A-fragment base: row (wm*128 + fr), k offset (lane>>4)*8
  const unsigned short* Afb = Ab + (size_t)(wm * 128 + fr) * K_DIM + (lane >> 4) * 8;

  // per-lane B staging sources (swizzle baked into global col, rule #21)
  const int cl = (tid & 3) ^ ((tid >> 3) & 3);
  const int r0 = tid >> 2;
  const unsigned short* bsrc0 = Bb + (size_t)r0 * K_DIM + cl * 8;
  const unsigned short* bsrc1 = Bb + (size_t)(r0 + 128) * K_DIM + cl * 8;

  // B fragment LDS element offset (panel-local); frag n at bbase + n*512
  const int bbase = (wn * 64 + fr) * 32 + cp * 8;

  f32x4 acc[8][4];
#pragma unroll
  for (int i = 0; i < 8; ++i)
#pragma unroll
    for (int j = 0; j < 4; ++j) acc[i][j] = (f32x4){0.f, 0.f, 0.f, 0.f};

  bf16x8 ga0[4], ga1[4];   // A fragments (global-loaded, ping-pong)
  bf16x8 bv0[4], bv1[4];   // B fragments (LDS-read, per k-half)

  // ---- prologue: stage B tile0 (both kh); load first A frag; drain; pre-read bv0 ----
  stage2(bsrc0, bsrc1, BP(0, 0), wave, 0);
  stage2(bsrc0, bsrc1, BP(0, 1), wave, 32);
  LD_GA(ga0, 0, 0);
  VMC(0);
  __builtin_amdgcn_s_barrier();
  RD_BV(bv0, BP(0, 0));

  // ---- main loop: 4 phases/K-tile; A from global 1 phase ahead; B staged 1 tile ahead ----
  for (int T = 0; T < NT - 1; ++T) {
    const int buf = T & 1, nb = buf ^ 1;
    const int k0 = T * 64;
    const int nk = k0 + 64;

    // P1: MFMA(k0,mh0){ga0,bv0}; load ga1<-A(k0,mh1); stage next B.kh0
    VMC(0);                                  // retire prev P3's next-ga0 group
    MFMA_BLK(0, ga0, bv0);
    LD_GA(ga1, 1, k0);
    stage2(bsrc0, bsrc1, BP(nb, 0), wave, nk);
    // P2: MFMA(k0,mh1){ga1,bv0}; load ga0<-A(k1,mh0); stage next B.kh1; read bv1
    VMC(2);                                  // retire P1's ga1 (leaves 2S)
    MFMA_BLK(1, ga1, bv0);
    LD_GA(ga0, 0, k0 + 32);
    stage2(bsrc0, bsrc1, BP(nb, 1), wave, nk + 32);
    RD_BV(bv1, BP(buf, 1));
    // P3: MFMA(k1,mh0){ga0,bv1}; load ga1<-A(k1,mh1) + ga0<-A(next,k0,mh0);
    //     barrier publishes next B.kh0 (its 2 loads retired by this VMC)
    VMC(2);                                  // retire P2's ga0 (+P1's 2S)
    MFMA_BLK(0, ga0, bv1);
    LD_GA(ga1, 1, k0 + 32);
    LD_GA(ga0, 0, nk);                       // next tile (k0', mh0)
    __builtin_amdgcn_s_barrier();            // publish BP(nb,0)
    RD_BV(bv0, BP(nb, 0));
    // P4: MFMA(k1,mh1){ga1,bv1}; barrier publishes next B.kh1
    VMC(4);                                  // retire P3's ga1 (+P2's 2S); leaves next-ga0
    MFMA_BLK(1, ga1, bv1);
    __builtin_amdgcn_s_barrier();            // publish BP(nb,1)
  }
  // ---- last tile: no staging, no barriers ----
  {
    const int buf = (NT - 1) & 1;
    const int k0 = (NT - 1) * 64;
    VMC(0);
    MFMA_BLK(0, ga0, bv0);
    LD_GA(ga1, 1, k0);
    VMC(0);
    MFMA_BLK(1, ga1, bv0);
    LD_GA(ga0, 0, k0 + 32);
    RD_BV(bv1, BP(buf, 1));
    VMC(0);
    MFMA_BLK(0, ga0, bv1);
    LD_GA(ga1, 1, k0 + 32);
    VMC(0);
    MFMA_BLK(1, ga1, bv1);
  }

  // ---- epilogue: C/D layout col = lane&15, row = (lane>>4)*4 + v ----
  const int orow = (lane >> 4) * 4;
#pragma unroll
  for (int mi = 0; mi < 8; ++mi) {
#pragma unroll
    for (int n = 0; n < 4; ++n) {
      const size_t r = row0 + wm * 128 + mi * 16 + orow;
      const size_t c = col0 + wn * 64 + n * 16 + fr;
#pragma unroll
      for (int v = 0; v < 4; ++v)
        C[(r + v) * N_DIM + c] = acc[mi][n][v];
    }
  }
}

// ---------- fallback (only if d_ws too small): naive fused ----------
__global__ __launch_bounds__(256) void fallback_kernel(const float* __restrict__ x,
                                                       const int* __restrict__ qw,
                                                       const float* __restrict__ sc,
                                                       const float* __restrict__ zp,
                                                       float* __restrict__ out) {
  __shared__ float xs[K_DIM];
  const int m = blockIdx.y;
  const int n = blockIdx.x * 256 + threadIdx.x;
  for (int i = threadIdx.x; i < K_DIM; i += 256) xs[i] = x[(size_t)m * K_DIM + i];
  __syncthreads();
  float acc = 0.f;
  const int* wrow = qw + (size_t)n * (K_DIM / 2);
  for (int g = 0; g < NGROUP; ++g) {
    float s = sc[n * NGROUP + g];
    float z = zp[n * NGROUP + g];
    float partial = 0.f;
    for (int p = 0; p < 64; ++p) {
      int q = wrow[g * 64 + p];
      partial += xs[g * 128 + 2 * p]     * ((float)(q & 15) - z);
      partial += xs[g * 128 + 2 * p + 1] * ((float)((q >> 4) & 15) - z);
    }
    acc = fmaf(partial, s, acc);
  }
  out[(size_t)m * N_DIM + n] = acc;
}

extern "C" void kernel_launch(void* const* d_in, const int* in_sizes, int n_in,
                              void* d_out, int out_size, void* d_ws, size_t ws_size,
                              hipStream_t stream) {
  const float* x  = (const float*)d_in[0];
  const int*   qw = (const int*)d_in[1];
  const float* sc = (const float*)d_in[2];
  const float* zp = (const float*)d_in[3];
  float* out = (float*)d_out;

  const size_t xb_bytes = (size_t)M_DIM * K_DIM * 2;
  const size_t wb_bytes = (size_t)N_DIM * K_DIM * 2;

  if (ws_size >= xb_bytes + wb_bytes) {
    unsigned short* xb = (unsigned short*)d_ws;
    unsigned short* wb = (unsigned short*)((char*)d_ws + xb_bytes);
    cvt_x_kernel<<<dim3((unsigned)((size_t)M_DIM * K_DIM / (256 * 8))), 256, 0, stream>>>(x, xb);
    dequant_kernel<<<dim3((unsigned)((size_t)N_DIM * (K_DIM / 2) / 4 / 256)), 256, 0, stream>>>(qw, sc, zp, wb);
    dim3 grid((M_DIM / BM) * (N_DIM / BN));  // 32*43 = 1376
    gemm_adirect_kernel<<<grid, dim3(512), 65536, stream>>>(xb, wb, out);
  } else {
    dim3 grid(N_DIM / 256, M_DIM);
    fallback_kernel<<<grid, 256, 0, stream>>>(x, qw, sc, zp, out);
  }
}

// Round 16
// 765.120 us; speedup vs baseline: 12.2029x; 2.2236x over previous
//
#include <hip/hip_runtime.h>
#include <hip/hip_bf16.h>
#include <stdint.h>

// Problem constants: B=4, S=2048, IN=4096, OUT=11008
#define M_DIM 8192   // B*S
#define N_DIM 11008  // OUT
#define K_DIM 4096   // IN
#define NGROUP 32    // K_DIM/128

#define BM 256
#define BN 256
#define BK 32
#define NT (K_DIM / BK)  // 128 K-tiles

typedef __attribute__((ext_vector_type(4))) float f32x4;
typedef __attribute__((ext_vector_type(8))) short short8;
typedef __attribute__((ext_vector_type(8))) __bf16 bf16x8;

static_assert(M_DIM % BM == 0 && N_DIM % BN == 0 && K_DIM % BK == 0, "tiling");
static_assert((NT - 4) % 4 == 0, "main loop unroll");

__device__ __forceinline__ unsigned short f2bf(float f) {
  union { float f; unsigned int u; } v; v.f = f;
  unsigned int r = v.u + 0x7FFFu + ((v.u >> 16) & 1u);  // RNE
  return (unsigned short)(r >> 16);
}

// ---------- prepass 1: x fp32 -> bf16 ----------
__global__ __launch_bounds__(256) void cvt_x_kernel(const float* __restrict__ x,
                                                    unsigned short* __restrict__ xb) {
  size_t i = ((size_t)blockIdx.x * 256 + threadIdx.x) * 8;
  float4 a = *(const float4*)(x + i);
  float4 b = *(const float4*)(x + i + 4);
  short8 o;
  o[0] = (short)f2bf(a.x); o[1] = (short)f2bf(a.y);
  o[2] = (short)f2bf(a.z); o[3] = (short)f2bf(a.w);
  o[4] = (short)f2bf(b.x); o[5] = (short)f2bf(b.y);
  o[6] = (short)f2bf(b.z); o[7] = (short)f2bf(b.w);
  *(short8*)(xb + i) = o;
}

// ---------- prepass 2: dequant packed int4 -> bf16 W[N][K] ----------
__global__ __launch_bounds__(256) void dequant_kernel(const int* __restrict__ qw,
                                                      const float* __restrict__ sc,
                                                      const float* __restrict__ zp,
                                                      unsigned short* __restrict__ W) {
  size_t chunk = (size_t)blockIdx.x * 256 + threadIdx.x;  // 4 packed int32 = 8 weights
  int row = (int)(chunk >> 9);
  int c4  = (int)(chunk & 511);
  int g   = c4 >> 4;
  float s = sc[row * NGROUP + g];
  float z = zp[row * NGROUP + g];
  int4 q = *(const int4*)(qw + (size_t)row * 2048 + c4 * 4);
  int qq[4] = {q.x, q.y, q.z, q.w};
  short8 o;
#pragma unroll
  for (int t = 0; t < 4; ++t) {
    o[2 * t]     = (short)f2bf(((float)(qq[t] & 15)        - z) * s);
    o[2 * t + 1] = (short)f2bf(((float)((qq[t] >> 4) & 15) - z) * s);
  }
  *(short8*)(W + (size_t)row * K_DIM + (size_t)c4 * 8) = o;
}

// ---------- 256x256 GEMM, BK=32, QUAD-buffered LDS, depth-2-tile prefetch ----------
__device__ __forceinline__ void gload_lds16(const void* g, void* l) {
  __builtin_amdgcn_global_load_lds((__attribute__((address_space(1))) void*)g,
                                   (__attribute__((address_space(3))) void*)l,
                                   16, 0, 0);
}

// Stage one [256 rows][32 K] panel (16KB), 2 gload_lds per thread.
__device__ __forceinline__ void stage2(const unsigned short* s0,
                                       const unsigned short* s1,
                                       unsigned short* panel, int wave, int koff) {
  gload_lds16(s0 + koff, panel + wave * 512);
  gload_lds16(s1 + koff, panel + 4096 + wave * 512);
}

#define VMC(N) asm volatile("s_waitcnt vmcnt(" #N ")" ::: "memory")

#define AP(q) (lds + (q) * 8192)
#define BPQ(q) (lds + 32768 + (q) * 8192)

// One K-tile (BK=32) = 2 phases of {reads, stage-issue, 16 MFMA}; single
// VMC + barrier at tile end. Reads hit buf Q (published >=2 barriers ago);
// stage writes buf SQ = (Q+3)%4 (its tile-(T-1) readers crossed last barrier).
#define TILE_D(Q, SQ, KOFF, DO_STAGE, VM_STMT, DO_BAR)                       \
  {                                                                          \
    bf16x8 av[4], bv[4];                                                     \
    _Pragma("unroll") for (int m_ = 0; m_ < 4; ++m_)                         \
      av[m_] = *(const bf16x8*)&AP(Q)[abase + m_ * 512];                     \
    _Pragma("unroll") for (int n_ = 0; n_ < 4; ++n_)                         \
      bv[n_] = *(const bf16x8*)&BPQ(Q)[bbase + n_ * 512];                    \
    if (DO_STAGE) stage2(asrc0, asrc1, AP(SQ), wave, KOFF);                  \
    __builtin_amdgcn_s_setprio(1);                                           \
    _Pragma("unroll") for (int m_ = 0; m_ < 4; ++m_)                         \
      _Pragma("unroll") for (int n_ = 0; n_ < 4; ++n_)                       \
        acc[m_][n_] = __builtin_amdgcn_mfma_f32_16x16x32_bf16(               \
            av[m_], bv[n_], acc[m_][n_], 0, 0, 0);                           \
    __builtin_amdgcn_s_setprio(0);                                           \
    bf16x8 aw[4];                                                            \
    _Pragma("unroll") for (int m_ = 0; m_ < 4; ++m_)                         \
      aw[m_] = *(const bf16x8*)&AP(Q)[abase + (4 + m_) * 512];               \
    if (DO_STAGE) stage2(bsrc0, bsrc1, BPQ(SQ), wave, KOFF);                 \
    __builtin_amdgcn_s_setprio(1);                                           \
    _Pragma("unroll") for (int m_ = 0; m_ < 4; ++m_)                         \
      _Pragma("unroll") for (int n_ = 0; n_ < 4; ++n_)                       \
        acc[4 + m_][n_] = __builtin_amdgcn_mfma_f32_16x16x32_bf16(           \
            aw[m_], bv[n_], acc[4 + m_][n_], 0, 0, 0);                       \
    __builtin_amdgcn_s_setprio(0);                                           \
    VM_STMT;                                                                 \
    if (DO_BAR) __builtin_amdgcn_s_barrier();                                \
  }

__global__ __launch_bounds__(512, 2) void gemm_deep_kernel(const unsigned short* __restrict__ A,
                                                           const unsigned short* __restrict__ B,
                                                           float* __restrict__ C) {
  extern __shared__ unsigned short lds[];  // A: 4 x 16KB, B: 4 x 16KB = 128KB

  const int tid  = threadIdx.x;
  const int wave = tid >> 6;
  const int lane = tid & 63;
  const int wm = wave >> 2;   // 0..1 -> 128-row slab
  const int wn = wave & 3;    // 0..3 -> 64-col slab
  const int fr = lane & 15;
  const int cp = (lane >> 4) ^ ((fr >> 1) & 3);  // swizzled physical 16B-block (0-conflict)

  // XCD-chunked block swizzle (1376 = 8*172, bijective), bm-major mapping
  const int wg  = blockIdx.x;
  const int sz_ = (wg & 7) * 172 + (wg >> 3);
  const int bm = sz_ / 43;
  const int bn = sz_ % 43;
  const size_t row0 = (size_t)bm * BM;
  const size_t col0 = (size_t)bn * BN;

  const unsigned short* Ab = A + row0 * K_DIM;
  const unsigned short* Bb = B + col0 * K_DIM;

  // precomputed per-lane staging sources (swizzle baked into global col, rule #21)
  const int cl = (tid & 3) ^ ((tid >> 3) & 3);
  const int r0 = tid >> 2;
  const unsigned short* asrc0 = Ab + (size_t)r0 * K_DIM + cl * 8;
  const unsigned short* asrc1 = Ab + (size_t)(r0 + 128) * K_DIM + cl * 8;
  const unsigned short* bsrc0 = Bb + (size_t)r0 * K_DIM + cl * 8;
  const unsigned short* bsrc1 = Bb + (size_t)(r0 + 128) * K_DIM + cl * 8;

  // fragment LDS element offsets (panel-local); frag mi at abase + mi*512
  const int abase = (wm * 128 + fr) * 32 + cp * 8;
  const int bbase = (wn * 64 + fr) * 32 + cp * 8;

  f32x4 acc[8][4];
#pragma unroll
  for (int i = 0; i < 8; ++i)
#pragma unroll
    for (int j = 0; j < 4; ++j) acc[i][j] = (f32x4){0.f, 0.f, 0.f, 0.f};

  // ---- prologue: stage tiles 0,1,2 (4 loads each); retire tile0's; publish ----
  stage2(asrc0, asrc1, AP(0), wave, 0);
  stage2(bsrc0, bsrc1, BPQ(0), wave, 0);
  stage2(asrc0, asrc1, AP(1), wave, 32);
  stage2(bsrc0, bsrc1, BPQ(1), wave, 32);
  stage2(asrc0, asrc1, AP(2), wave, 64);
  stage2(bsrc0, bsrc1, BPQ(2), wave, 64);
  VMC(8);                       // tile0's 4 landed; tiles 1,2 in flight
  __builtin_amdgcn_s_barrier();

  // ---- main loop: tiles 0..NT-5, staging T+3; VMC(4)/tile retires tile T+2 ----
  for (int T = 0; T < NT - 4; T += 4) {
    const int k3 = (T + 3) * 32;
    TILE_D(0, 3, k3,      true, VMC(4), true);
    TILE_D(1, 0, k3 + 32, true, VMC(4), true);
    TILE_D(2, 1, k3 + 64, true, VMC(4), true);
    TILE_D(3, 2, k3 + 96, true, VMC(4), true);
  }
  // ---- tail: tiles NT-4..NT-1 ----
  TILE_D(0, 3, (NT - 1) * 32, true, VMC(4), true);   // stage last tile
  TILE_D(1, 0, 0, false, VMC(0), true);              // drain last tile's loads
  TILE_D(2, 0, 0, false, , false);
  TILE_D(3, 0, 0, false, , false);

  // ---- epilogue: C/D layout col = lane&15, row = (lane>>4)*4 + v ----
  const int orow = (lane >> 4) * 4;
#pragma unroll
  for (int mi = 0; mi < 8; ++mi) {
#pragma unroll
    for (int n = 0; n < 4; ++n) {
      const size_t r = row0 + wm * 128 + mi * 16 + orow;
      const size_t c = col0 + wn * 64 + n * 16 + fr;
#pragma unroll
      for (int v = 0; v < 4; ++v)
        C[(r + v) * N_DIM + c] = acc[mi][n][v];
    }
  }
}

// ---------- fallback (only if d_ws too small): naive fused ----------
__global__ __launch_bounds__(256) void fallback_kernel(const float* __restrict__ x,
                                                       const int* __restrict__ qw,
                                                       const float* __restrict__ sc,
                                                       const float* __restrict__ zp,
                                                       float* __restrict__ out) {
  __shared__ float xs[K_DIM];
  const int m = blockIdx.y;
  const int n = blockIdx.x * 256 + threadIdx.x;
  for (int i = threadIdx.x; i < K_DIM; i += 256) xs[i] = x[(size_t)m * K_DIM + i];
  __syncthreads();
  float acc = 0.f;
  const int* wrow = qw + (size_t)n * (K_DIM / 2);
  for (int g = 0; g < NGROUP; ++g) {
    float s = sc[n * NGROUP + g];
    float z = zp[n * NGROUP + g];
    float partial = 0.f;
    for (int p = 0; p < 64; ++p) {
      int q = wrow[g * 64 + p];
      partial += xs[g * 128 + 2 * p]     * ((float)(q & 15) - z);
      partial += xs[g * 128 + 2 * p + 1] * ((float)((q >> 4) & 15) - z);
    }
    acc = fmaf(partial, s, acc);
  }
  out[(size_t)m * N_DIM + n] = acc;
}

extern "C" void kernel_launch(void* const* d_in, const int* in_sizes, int n_in,
                              void* d_out, int out_size, void* d_ws, size_t ws_size,
                              hipStream_t stream) {
  const float* x  = (const float*)d_in[0];
  const int*   qw = (const int*)d_in[1];
  const float* sc = (const float*)d_in[2];
  const float* zp = (const float*)d_in[3];
  float* out = (float*)d_out;

  const size_t xb_bytes = (size_t)M_DIM * K_DIM * 2;
  const size_t wb_bytes = (size_t)N_DIM * K_DIM * 2;

  if (ws_size >= xb_bytes + wb_bytes) {
    unsigned short* xb = (unsigned short*)d_ws;
    unsigned short* wb = (unsigned short*)((char*)d_ws + xb_bytes);
    cvt_x_kernel<<<dim3((unsigned)((size_t)M_DIM * K_DIM / (256 * 8))), 256, 0, stream>>>(x, xb);
    dequant_kernel<<<dim3((unsigned)((size_t)N_DIM * (K_DIM / 2) / 4 / 256)), 256, 0, stream>>>(qw, sc, zp, wb);
    dim3 grid((M_DIM / BM) * (N_DIM / BN));  // 32*43 = 1376
    gemm_deep_kernel<<<grid, dim3(512), 131072, stream>>>(xb, wb, out);
  } else {
    dim3 grid(N_DIM / 256, M_DIM);
    fallback_kernel<<<grid, 256, 0, stream>>>(x, qw, sc, zp, out);
  }
}